// Round 12
// baseline (7504.678 us; speedup 1.0000x reference)
//
#include <hip/hip_runtime.h>
#include <math.h>

#define N_NODES 25000
#define N_EDGES 800000
#define IN_SZ 64
#define S_DIM 128
#define V_DIM 16
#define H_DIM 17
#define GVP_EPS 1e-8f
#define LN_EPS 1e-5f
#define INV_Z 0.1f
#define TE 64    // edges per block (16 per wave)
#define WSTK 160 // K padded (145 -> 160) for 5 chunks of 32

// ---- LDS layout (float offsets) ----
// ZF [64][148] per-edge row: P1 scratch ve[3][20]@0, vh[3][20]@64, sh@128..144 (f32);
//   at z-stage the bf16 Z row (k=0..159 = s cols + sh + pad) overlays words 0..79
//   (dead ve/vh); after GEMM the scalar-message overlay takes words 0..127.
// VU [64][48]; WhL 289; WuL 272; stile/dtile int[64] each.
#define ZF_O 0
#define ZSTR 148
#define VU_O 9472
#define WHL_O 12544
#define WUL_O 12833
#define ST_O 13105
#define DT_O 13169
#define LDS_F 13233  // 52932 B -> 3 blocks/CU

typedef __attribute__((ext_vector_type(8))) short bf16x8;
typedef __attribute__((ext_vector_type(4))) float f32x4;

__device__ __forceinline__ float wave_sum(float x) {
#pragma unroll
  for (int off = 32; off; off >>= 1) x += __shfl_xor(x, off, 64);
  return x;
}

__device__ __forceinline__ float sum16(float x) {
#pragma unroll
  for (int off = 1; off < 16; off <<= 1) x += __shfl_xor(x, off, 64);
  return x;
}

__device__ __forceinline__ float silu_f(float x) { return x / (1.0f + __expf(-x)); }

__device__ __forceinline__ unsigned short bf16r(float x) {
  unsigned int u = __float_as_uint(x);
  return (unsigned short)((u + 0x7fffu + ((u >> 16) & 1u)) >> 16);
}
__device__ __forceinline__ unsigned int pk2(float a, float b) {
  return (unsigned int)bf16r(a) | ((unsigned int)bf16r(b) << 16);
}

// wave-local DS ordering fence (DS ops are in-order per wave; pins the compiler)
__device__ __forceinline__ void lds_fence() {
  asm volatile("s_waitcnt lgkmcnt(0)" ::: "memory");
}

// reduce 16 partials across a 16-lane group; lane l16 gets total of index l16
__device__ __forceinline__ float reduce_scatter16(const float pu[16], int l16) {
  float r8[8];
#pragma unroll
  for (int u = 0; u < 8; ++u) {
    const float keep = (l16 & 8) ? pu[u + 8] : pu[u];
    const float send = (l16 & 8) ? pu[u] : pu[u + 8];
    r8[u] = keep + __shfl_xor(send, 8, 64);
  }
  float r4[4];
#pragma unroll
  for (int u = 0; u < 4; ++u) {
    const float keep = (l16 & 4) ? r8[u + 4] : r8[u];
    const float send = (l16 & 4) ? r8[u] : r8[u + 4];
    r4[u] = keep + __shfl_xor(send, 4, 64);
  }
  float r2[2];
#pragma unroll
  for (int u = 0; u < 2; ++u) {
    const float keep = (l16 & 2) ? r4[u + 2] : r4[u];
    const float send = (l16 & 2) ? r4[u] : r4[u + 2];
    r2[u] = keep + __shfl_xor(send, 2, 64);
  }
  const float keep = (l16 & 1) ? r2[1] : r2[0];
  const float send = (l16 & 1) ? r2[0] : r2[1];
  return keep + __shfl_xor(send, 1, 64);
}

// ---------------------------------------------------------------- embed
__global__ __launch_bounds__(128) void embed_kernel(
    const float* __restrict__ node_h,
    const float* __restrict__ W1, const float* __restrict__ b1,
    const float* __restrict__ W2, const float* __restrict__ b2,
    const float* __restrict__ g, const float* __restrict__ b,
    float* __restrict__ s, float* __restrict__ v) {
  const int n = blockIdx.x, tid = threadIdx.x;
  __shared__ float hb[IN_SZ];
  __shared__ float h1[S_DIM];
  __shared__ float red[4];
  if (tid < IN_SZ) hb[tid] = node_h[n * IN_SZ + tid];
  __syncthreads();
  float acc = b1[tid];
#pragma unroll 8
  for (int k = 0; k < IN_SZ; ++k) acc += hb[k] * W1[k * S_DIM + tid];
  float x = silu_f(acc);
  h1[tid] = x;
  __syncthreads();
  float acc2 = b2[tid];
#pragma unroll 8
  for (int k = 0; k < S_DIM; ++k) acc2 += h1[k] * W2[k * S_DIM + tid];
  float y = silu_f(acc2);
  const int wv = tid >> 6, lane = tid & 63;
  float sm = wave_sum(y);
  float sq = wave_sum(y * y);
  if (lane == 0) { red[wv] = sm; red[2 + wv] = sq; }
  __syncthreads();
  float tot = red[0] + red[1], tot2 = red[2] + red[3];
  float mu = tot * (1.0f / 128.0f);
  float var = tot2 * (1.0f / 128.0f) - mu * mu;
  float inv = rsqrtf(var + LN_EPS);
  s[n * S_DIM + tid] = (y - mu) * inv * g[tid] + b[tid];
  if (tid < 48) v[n * 48 + tid] = 0.0f;
}

// ---------------------------------------------------------------- sort infra
__global__ __launch_bounds__(256) void hist_kernel(const int* __restrict__ edst,
                                                   int* __restrict__ cnt) {
  int e = blockIdx.x * 256 + threadIdx.x;
  if (e < N_EDGES) atomicAdd(&cnt[edst[e]], 1);
}

__global__ __launch_bounds__(1024) void scan_kernel(const int* __restrict__ cnt,
                                                    int* __restrict__ rowptr) {
  __shared__ int wsum[16];
  __shared__ int carry_s;
  const int t = threadIdx.x, w = t >> 6, ln = t & 63;
  if (t == 0) carry_s = 0;
  __syncthreads();
  for (int base = 0; base < N_NODES; base += 1024) {
    const int idx = base + t;
    const int x = (idx < N_NODES) ? cnt[idx] : 0;
    int incl = x;
#pragma unroll
    for (int off = 1; off < 64; off <<= 1) {
      const int y = __shfl_up(incl, off, 64);
      if (ln >= off) incl += y;
    }
    if (ln == 63) wsum[w] = incl;
    __syncthreads();
    int woff = 0;
    for (int k = 0; k < w; ++k) woff += wsum[k];
    const int carry = carry_s;
    if (idx < N_NODES) rowptr[idx] = carry + woff + incl - x;
    __syncthreads();
    if (t == 1023) carry_s = carry + woff + incl;
    __syncthreads();
  }
  if (threadIdx.x == 0) rowptr[N_NODES] = carry_s;
}

__global__ __launch_bounds__(256) void initcur_kernel(const int* __restrict__ rowptr,
                                                      int* __restrict__ cursor) {
  int i = blockIdx.x * 256 + threadIdx.x;
  if (i < N_NODES) cursor[i] = rowptr[i];
}

__global__ __launch_bounds__(256) void scatter_kernel(const int* __restrict__ esrc,
                                                      const int* __restrict__ edst,
                                                      int* __restrict__ cursor,
                                                      int* __restrict__ srcs,
                                                      int* __restrict__ dsts) {
  int e = blockIdx.x * 256 + threadIdx.x;
  if (e < N_EDGES) {
    const int d = edst[e];
    const int p = atomicAdd(&cursor[d], 1);
    srcs[p] = esrc[e];
    dsts[p] = d;
  }
}

// ---------------------------------------------------------------- WsT prep
// Build bf16 transposed+padded Ws for the edge GEMM: WsT[l][n][k], k<145 from
// Ws[l][k][n], else 0.  (3 layers x 128 x 160)
__global__ __launch_bounds__(256) void wst_prep_kernel(const float* __restrict__ Ws,
                                                       unsigned short* __restrict__ WsT) {
  const int idx = blockIdx.x * 256 + threadIdx.x;
  if (idx >= 3 * S_DIM * WSTK) return;
  const int l = idx / (S_DIM * WSTK);
  const int rr = idx - l * (S_DIM * WSTK);
  const int n = rr / WSTK, k = rr - n * WSTK;
  const float x = (k < 145) ? Ws[(size_t)l * 145 * S_DIM + (size_t)k * S_DIM + n] : 0.0f;
  WsT[idx] = bf16r(x);
}

// ---------------------------------------------------------------- edge kernel
// Fully wave-independent (one block barrier): each wave owns 16 edges.
// Feats GEMM on MFMA: M=16 edges, N=128 (8 tiles), K=160 (5 chunks), bf16 in,
// fp32 accum seeded with bias.  D layout: col=lane&15, row=(lane>>4)*4+reg.
__global__ __launch_bounds__(256, 3) void edge_gemm_kernel(
    const float* __restrict__ s, const float* __restrict__ v,
    const float* __restrict__ coords,
    const int* __restrict__ srcs, const int* __restrict__ dsts,
    float* __restrict__ smsg, float* __restrict__ vmsg,
    const float* __restrict__ Wh, const float* __restrict__ Wu,
    const unsigned short* __restrict__ WsT, const float* __restrict__ bs,
    const float* __restrict__ Wg, const float* __restrict__ bg,
    const float* __restrict__ lng, const float* __restrict__ lnb) {
  __shared__ float L[LDS_F];
  const int t = threadIdx.x;
  const int wv = t >> 6, ln = t & 63;
  const int g = ln >> 4, l16 = ln & 15;
  const int e0 = blockIdx.x * TE;
  int* stile = (int*)&L[ST_O];
  int* dtile = (int*)&L[DT_O];
  if (t < TE) { stile[t] = srcs[e0 + t]; dtile[t] = dsts[e0 + t]; }
  for (int k = t; k < H_DIM * H_DIM; k += 256) L[WHL_O + k] = Wh[k];
  for (int k = t; k < H_DIM * V_DIM; k += 256) L[WUL_O + k] = Wu[k];
  __syncthreads();  // the ONLY block barrier

  const int ew0 = wv * 16;
  const int lc = ln % 3, lq = ln / 3;

  // ---- P1a: gather ve (transposed [c][20]) into ZF[e][0..59]
  for (int i = 0; i < 16; ++i) {
    const int e = ew0 + i, src = stile[e];
    if (ln < 48) {
      L[ZF_O + e * ZSTR + lc * 20 + lq + 1] = v[(size_t)src * 48 + ln];
    } else if (ln < 51) {
      const int c = ln - 48;
      L[ZF_O + e * ZSTR + c * 20] = coords[src * 3 + c] - coords[dtile[e] * 3 + c];
    }
  }
  lds_fence();

  // ---- P1b: vh (into ZF[e][64..123])
  {
    float wh[H_DIM];
    if (ln < 51) {
#pragma unroll
      for (int vv = 0; vv < H_DIM; ++vv) wh[vv] = L[WHL_O + vv * H_DIM + lq];
    }
    for (int i = 0; i < 16; ++i) {
      const int e = ew0 + i;
      if (ln < 51) {
        const int b = ZF_O + e * ZSTR + lc * 20;
        const float4 v0 = *(const float4*)&L[b + 0];
        const float4 v1 = *(const float4*)&L[b + 4];
        const float4 v2 = *(const float4*)&L[b + 8];
        const float4 v3 = *(const float4*)&L[b + 12];
        const float vl = L[b + 16];
        float a = wh[0] * v0.x + wh[1] * v0.y + wh[2] * v0.z + wh[3] * v0.w
                + wh[4] * v1.x + wh[5] * v1.y + wh[6] * v1.z + wh[7] * v1.w
                + wh[8] * v2.x + wh[9] * v2.y + wh[10] * v2.z + wh[11] * v2.w
                + wh[12] * v3.x + wh[13] * v3.y + wh[14] * v3.z + wh[15] * v3.w
                + wh[16] * vl;
        L[ZF_O + e * ZSTR + 64 + lc * 20 + lq] = a;
      }
    }
  }
  lds_fence();

  // ---- P1c: sh -> ZF[e][128..144]
  for (int i = 0; i < 16; ++i) {
    const int e = ew0 + i;
    if (ln < H_DIM) {
      const float x0 = L[ZF_O + e * ZSTR + 64 + 0 + ln];
      const float x1 = L[ZF_O + e * ZSTR + 64 + 20 + ln];
      const float x2 = L[ZF_O + e * ZSTR + 64 + 40 + ln];
      L[ZF_O + e * ZSTR + 128 + ln] = sqrtf(x0 * x0 + x1 * x1 + x2 * x2 + GVP_EPS);
    }
  }
  // ---- P1d: vu -> VU[e][u*3+c]
  {
    float wu[H_DIM];
    if (ln < 48) {
#pragma unroll
      for (int h = 0; h < H_DIM; ++h) wu[h] = L[WUL_O + h * V_DIM + lq];
    }
    for (int i = 0; i < 16; ++i) {
      const int e = ew0 + i;
      if (ln < 48) {
        const int b = ZF_O + e * ZSTR + 64 + lc * 20;
        const float4 v0 = *(const float4*)&L[b + 0];
        const float4 v1 = *(const float4*)&L[b + 4];
        const float4 v2 = *(const float4*)&L[b + 8];
        const float4 v3 = *(const float4*)&L[b + 12];
        const float vl = L[b + 16];
        float a = wu[0] * v0.x + wu[1] * v0.y + wu[2] * v0.z + wu[3] * v0.w
                + wu[4] * v1.x + wu[5] * v1.y + wu[6] * v1.z + wu[7] * v1.w
                + wu[8] * v2.x + wu[9] * v2.y + wu[10] * v2.z + wu[11] * v2.w
                + wu[12] * v3.x + wu[13] * v3.y + wu[14] * v3.z + wu[15] * v3.w
                + wu[16] * vl;
        L[VU_O + e * 48 + lq * 3 + lc] = a;
      }
    }
  }
  lds_fence();

  // ---- Z stage: build bf16 Z row (k=0..127 from s, 128..144 sh, 145..159 zero)
  // into words 0..79 of own ZF row (ve/vh dead).  4 lanes per edge, 40 k each.
  {
    const int le = ln >> 2, q = ln & 3;
    const int e = ew0 + le;
    char* zb = (char*)&L[ZF_O + e * ZSTR];
    if (q < 3) {
      const float* sp = &s[(size_t)stile[e] * S_DIM + q * 40];
#pragma unroll
      for (int c = 0; c < 5; ++c) {
        const float4 x0 = *(const float4*)(sp + c * 8);
        const float4 x1 = *(const float4*)(sp + c * 8 + 4);
        uint4 w;
        w.x = pk2(x0.x, x0.y); w.y = pk2(x0.z, x0.w);
        w.z = pk2(x1.x, x1.y); w.w = pk2(x1.z, x1.w);
        *(uint4*)(zb + (q * 40 + c * 8) * 2) = w;
      }
    } else {
      const float* sp = &s[(size_t)stile[e] * S_DIM + 120];
      const float4 x0 = *(const float4*)(sp);
      const float4 x1 = *(const float4*)(sp + 4);
      uint4 w;
      w.x = pk2(x0.x, x0.y); w.y = pk2(x0.z, x0.w);
      w.z = pk2(x1.x, x1.y); w.w = pk2(x1.z, x1.w);
      *(uint4*)(zb + 240) = w;  // k=120..127
      float shv[17];
#pragma unroll
      for (int i2 = 0; i2 < 17; ++i2) shv[i2] = L[ZF_O + e * ZSTR + 128 + i2];
      uint4 w1, w2, w3, w4;
      w1.x = pk2(shv[0], shv[1]);  w1.y = pk2(shv[2], shv[3]);
      w1.z = pk2(shv[4], shv[5]);  w1.w = pk2(shv[6], shv[7]);
      w2.x = pk2(shv[8], shv[9]);  w2.y = pk2(shv[10], shv[11]);
      w2.z = pk2(shv[12], shv[13]); w2.w = pk2(shv[14], shv[15]);
      w3.x = pk2(shv[16], 0.0f); w3.y = 0u; w3.z = 0u; w3.w = 0u;
      w4.x = 0u; w4.y = 0u; w4.z = 0u; w4.w = 0u;
      *(uint4*)(zb + 256) = w1;  // k=128..135
      *(uint4*)(zb + 272) = w2;  // k=136..143
      *(uint4*)(zb + 288) = w3;  // k=144..151
      *(uint4*)(zb + 304) = w4;  // k=152..159
    }
  }
  lds_fence();

  // ---- P2: MFMA feats GEMM.  A: edge m=l16, k=g*8+j per chunk (LDS bf16);
  //          B: col n=nt*16+l16, same k (global WsT).  D: row=g*4+r, col=nt*16+l16.
  bf16x8 afr[5];
  {
    const char* arow = (const char*)&L[ZF_O + (ew0 + l16) * ZSTR] + g * 16;
#pragma unroll
    for (int kc = 0; kc < 5; ++kc)
      afr[kc] = *(const bf16x8*)(arow + kc * 64);
  }
  f32x4 facc[8];
#pragma unroll
  for (int nt = 0; nt < 8; ++nt) {
    const float bsv = bs[nt * 16 + l16];
    f32x4 a0 = {bsv, bsv, bsv, bsv};
    const unsigned short* wrow = WsT + (size_t)(nt * 16 + l16) * WSTK + g * 8;
#pragma unroll
    for (int kc = 0; kc < 5; ++kc) {
      const bf16x8 bfr = *(const bf16x8*)(wrow + kc * 32);
      a0 = __builtin_amdgcn_mfma_f32_16x16x32_bf16(afr[kc], bfr, a0, 0, 0, 0);
    }
    facc[nt] = a0;
  }
  // silu -> feats (in accumulators)
#pragma unroll
  for (int nt = 0; nt < 8; ++nt)
#pragma unroll
    for (int r = 0; r < 4; ++r) facc[nt][r] = silu_f(facc[nt][r]);

  // ---- P3a: gate.  Lane holds cols {nt*16+l16} of edges ew0+g*4+r.
  const float bgv = bg[l16];
  float gate_i[4];
#pragma unroll
  for (int r = 0; r < 4; ++r) {
    float pu[16];
#pragma unroll
    for (int u = 0; u < 16; ++u) pu[u] = 0.0f;
#pragma unroll
    for (int nt = 0; nt < 8; ++nt) {
      const float* wr = &Wg[(nt * 16 + l16) * V_DIM];
      const float4 w0 = *(const float4*)(wr);
      const float4 w1 = *(const float4*)(wr + 4);
      const float4 w2 = *(const float4*)(wr + 8);
      const float4 w3 = *(const float4*)(wr + 12);
      const float fv = facc[nt][r];
      pu[0] += fv * w0.x; pu[1] += fv * w0.y; pu[2] += fv * w0.z; pu[3] += fv * w0.w;
      pu[4] += fv * w1.x; pu[5] += fv * w1.y; pu[6] += fv * w1.z; pu[7] += fv * w1.w;
      pu[8] += fv * w2.x; pu[9] += fv * w2.y; pu[10] += fv * w2.z; pu[11] += fv * w2.w;
      pu[12] += fv * w3.x; pu[13] += fv * w3.y; pu[14] += fv * w3.z; pu[15] += fv * w3.w;
    }
    gate_i[r] = silu_f(reduce_scatter16(pu, l16) + bgv);
  }

  // ---- P3b: vm in-place in VU (channel u = l16); edge = ew0 + g*4 + i
#pragma unroll
  for (int i = 0; i < 4; ++i) {
    const int e = ew0 + g * 4 + i;
    const int b = VU_O + e * 48 + l16 * 3;
    const float gt = gate_i[i];
    const float vm0 = L[b + 0] * gt;
    const float vm1 = L[b + 1] * gt;
    const float vm2 = L[b + 2] * gt;
    float ss = sum16(vm0 * vm0 + vm1 * vm1 + vm2 * vm2);
    const float sc = INV_Z * rsqrtf(ss * (1.0f / 16.0f) + GVP_EPS);
    L[b + 0] = vm0 * sc;
    L[b + 1] = vm1 * sc;
    L[b + 2] = vm2 * sc;
  }

  // ---- P3c: LN + affine + scale -> message into ZF[e][0..127] (Z row dead)
  {
    float lngv[8], lnbv[8];
#pragma unroll
    for (int nt = 0; nt < 8; ++nt) {
      lngv[nt] = lng[nt * 16 + l16];
      lnbv[nt] = lnb[nt * 16 + l16];
    }
#pragma unroll
    for (int r = 0; r < 4; ++r) {
      float s1 = 0.0f, s2 = 0.0f;
#pragma unroll
      for (int nt = 0; nt < 8; ++nt) {
        const float fv = facc[nt][r];
        s1 += fv; s2 += fv * fv;
      }
      s1 = sum16(s1); s2 = sum16(s2);
      const float mu = s1 * (1.0f / 128.0f);
      const float var = s2 * (1.0f / 128.0f) - mu * mu;
      const float inv = rsqrtf(var + LN_EPS);
      const int e = ew0 + g * 4 + r;
#pragma unroll
      for (int nt = 0; nt < 8; ++nt)
        L[ZF_O + e * ZSTR + nt * 16 + l16] =
            ((facc[nt][r] - mu) * inv * lngv[nt] + lnbv[nt]) * INV_Z;
    }
  }
  lds_fence();

  // ---- P4: per-wave run aggregation over 16 edges
  int r = 0;
  while (r < 16) {
    const int d = dtile[ew0 + r];
    int rend = r + 1;
    while (rend < 16 && dtile[ew0 + rend] == d) ++rend;
    float a0 = 0.0f, a1 = 0.0f, a2 = 0.0f;
    for (int i = r; i < rend; ++i) {
      a0 += L[ZF_O + (ew0 + i) * ZSTR + ln];
      a1 += L[ZF_O + (ew0 + i) * ZSTR + 64 + ln];
      if (ln < 48) a2 += L[VU_O + (ew0 + i) * 48 + ln];
    }
    atomicAdd(&smsg[(size_t)d * S_DIM + ln], a0);
    atomicAdd(&smsg[(size_t)d * S_DIM + 64 + ln], a1);
    if (ln < 48) atomicAdd(&vmsg[(size_t)d * 48 + ln], a2);
    r = rend;
  }
}

// ---------------------------------------------------------------- node update
__global__ __launch_bounds__(256) void node_update_kernel(
    float* __restrict__ s, float* __restrict__ v,
    const float* __restrict__ smsg, const float* __restrict__ vmsg,
    const float* __restrict__ Wh, const float* __restrict__ Wu,
    const float* __restrict__ Ws, const float* __restrict__ bs,
    const float* __restrict__ Wg, const float* __restrict__ bg,
    const float* __restrict__ lng, const float* __restrict__ lnb,
    const float* __restrict__ og, const float* __restrict__ ob) {
  const int wv = threadIdx.x >> 6, lane = threadIdx.x & 63;
  const int n = blockIdx.x * 4 + wv;

  __shared__ float z[4][146];
  __shared__ float vel[4][48];
  __shared__ float vhl[4][48];
  __shared__ float fe[4][128];
  __shared__ float ga[4][16];

  float s0 = s[n * S_DIM + lane] + smsg[n * S_DIM + lane];
  float s1 = s[n * S_DIM + 64 + lane] + smsg[n * S_DIM + 64 + lane];
  float sm_ = wave_sum(s0 + s1), sq_ = wave_sum(s0 * s0 + s1 * s1);
  float mu = sm_ * (1.0f / 128.0f), var = sq_ * (1.0f / 128.0f) - mu * mu;
  float inv = rsqrtf(var + LN_EPS);
  float sa0 = (s0 - mu) * inv * og[lane] + ob[lane];
  float sa1 = (s1 - mu) * inv * og[64 + lane] + ob[64 + lane];
  z[wv][lane] = sa0; z[wv][64 + lane] = sa1;
  float vvr = 0.0f;
  if (lane < 48) vvr = v[n * 48 + lane] + vmsg[n * 48 + lane];
  float n2 = wave_sum(vvr * vvr);
  float rms = sqrtf(n2 * (1.0f / 16.0f) + GVP_EPS);
  float vln = vvr / rms;
  if (lane < 48) vel[wv][lane] = vln;
  __syncthreads();

  if (lane < 48) {
    int h = lane / 3, c = lane - 3 * h;
    float a = 0.0f;
#pragma unroll
    for (int vv = 0; vv < V_DIM; ++vv) a += vel[wv][vv * 3 + c] * Wh[vv * V_DIM + h];
    vhl[wv][lane] = a;
  }
  __syncthreads();

  if (lane < V_DIM) {
    float a = vhl[wv][lane * 3], b_ = vhl[wv][lane * 3 + 1], c_ = vhl[wv][lane * 3 + 2];
    z[wv][128 + lane] = sqrtf(a * a + b_ * b_ + c_ * c_ + GVP_EPS);
  }
  float vur = 0.0f;
  if (lane < 48) {
    int u = lane / 3, c = lane - 3 * u;
#pragma unroll
    for (int h = 0; h < V_DIM; ++h) vur += vhl[wv][h * 3 + c] * Wu[h * V_DIM + u];
  }
  __syncthreads();

  float f0 = bs[lane], f1 = bs[64 + lane];
#pragma unroll 4
  for (int k = 0; k < 144; ++k) {
    float zz = z[wv][k];
    f0 += zz * Ws[k * S_DIM + lane];
    f1 += zz * Ws[k * S_DIM + 64 + lane];
  }
  f0 = silu_f(f0); f1 = silu_f(f1);
  fe[wv][lane] = f0; fe[wv][64 + lane] = f1;
  __syncthreads();

  {
    int u = lane >> 2, q = lane & 3;
    float p = 0.0f;
#pragma unroll 8
    for (int k = q * 32; k < q * 32 + 32; ++k) p += fe[wv][k] * Wg[k * V_DIM + u];
    p += __shfl_xor(p, 1, 64);
    p += __shfl_xor(p, 2, 64);
    if (q == 0) ga[wv][u] = silu_f(p + bg[u]);
  }
  float sm2 = wave_sum(f0 + f1), sq2 = wave_sum(f0 * f0 + f1 * f1);
  float mu2 = sm2 * (1.0f / 128.0f), var2 = sq2 * (1.0f / 128.0f) - mu2 * mu2;
  float inv2 = rsqrtf(var2 + LN_EPS);
  float t0 = sa0 + (f0 - mu2) * inv2 * lng[lane] + lnb[lane];
  float t1 = sa1 + (f1 - mu2) * inv2 * lng[64 + lane] + lnb[64 + lane];
  float sm3 = wave_sum(t0 + t1), sq3 = wave_sum(t0 * t0 + t1 * t1);
  float mu3 = sm3 * (1.0f / 128.0f), var3 = sq3 * (1.0f / 128.0f) - mu3 * mu3;
  float inv3 = rsqrtf(var3 + LN_EPS);
  s[n * S_DIM + lane] = (t0 - mu3) * inv3 * og[lane] + ob[lane];
  s[n * S_DIM + 64 + lane] = (t1 - mu3) * inv3 * og[64 + lane] + ob[64 + lane];
  __syncthreads();

  float vo = 0.0f;
  if (lane < 48) { int u = lane / 3; vo = vur * ga[wv][u]; }
  float n22 = wave_sum(vo * vo);
  float rms2 = sqrtf(n22 * (1.0f / 16.0f) + GVP_EPS);
  float vr = vo / rms2;
  float v2 = (lane < 48) ? (vln + vr) : 0.0f;
  float n23 = wave_sum(v2 * v2);
  float rms3 = sqrtf(n23 * (1.0f / 16.0f) + GVP_EPS);
  if (lane < 48) v[n * 48 + lane] = v2 / rms3;
}

// ---------------------------------------------------------------- launch
extern "C" void kernel_launch(void* const* d_in, const int* in_sizes, int n_in,
                              void* d_out, int out_size, void* d_ws, size_t ws_size,
                              hipStream_t stream) {
  const float* node_h = (const float*)d_in[0];
  const float* coords = (const float*)d_in[1];
  const int* esrc = (const int*)d_in[2];
  const int* edst = (const int*)d_in[3];
  const float* emb_W1 = (const float*)d_in[4];
  const float* emb_b1 = (const float*)d_in[5];
  const float* emb_W2 = (const float*)d_in[6];
  const float* emb_b2 = (const float*)d_in[7];
  const float* norm_g = (const float*)d_in[8];
  const float* norm_b = (const float*)d_in[9];
  const float* em_Wh = (const float*)d_in[10];
  const float* em_Wu = (const float*)d_in[11];
  const float* em_Ws = (const float*)d_in[12];
  const float* em_bs = (const float*)d_in[13];
  const float* em_Wg = (const float*)d_in[14];
  const float* em_bg = (const float*)d_in[15];
  const float* em_lng = (const float*)d_in[16];
  const float* em_lnb = (const float*)d_in[17];
  const float* nu_Wh = (const float*)d_in[18];
  const float* nu_Wu = (const float*)d_in[19];
  const float* nu_Ws = (const float*)d_in[20];
  const float* nu_bs = (const float*)d_in[21];
  const float* nu_Wg = (const float*)d_in[22];
  const float* nu_bg = (const float*)d_in[23];
  const float* nu_lng = (const float*)d_in[24];
  const float* nu_lnb = (const float*)d_in[25];
  const float* ln_g = (const float*)d_in[26];
  const float* ln_b = (const float*)d_in[27];

  float* s = (float*)d_out;                      // [N,128] output 0
  float* v = s + (size_t)N_NODES * S_DIM;        // [N,16,3] output 1

  float* smsg = (float*)d_ws;                    // [N,128]
  float* vmsg = smsg + (size_t)N_NODES * S_DIM;  // [N,48]
  unsigned short* wsb = (unsigned short*)(vmsg + (size_t)N_NODES * 48);  // [3][128][160] bf16
  int* rowptr = (int*)(wsb + (size_t)3 * S_DIM * WSTK);  // [N+1] (+pad)
  int* srcs = rowptr + N_NODES + 8;              // [E]
  int* dsts = srcs + N_EDGES;                    // [E]
  int* cnt = (int*)smsg;                         // alias (setup phase only)
  int* cursor = cnt + N_NODES;                   // alias (setup phase only)

  const size_t need_sorted =
      (size_t)N_NODES * 176 * sizeof(float) +
      (size_t)3 * S_DIM * WSTK * sizeof(unsigned short) +
      (size_t)(N_NODES + 1 + 8) * sizeof(int) +
      (size_t)2 * N_EDGES * sizeof(int);
  // ws_size is fixed across calls -> branch is deterministic (graph-safe).
  const bool use_sorted = ws_size >= need_sorted;

  // WsT bf16 prep (always; both paths use it)
  wst_prep_kernel<<<(3 * S_DIM * WSTK + 255) / 256, 256, 0, stream>>>(em_Ws, wsb);

  if (use_sorted) {
    hipMemsetAsync(cnt, 0, N_NODES * sizeof(int), stream);
    hist_kernel<<<(N_EDGES + 255) / 256, 256, 0, stream>>>(edst, cnt);
    scan_kernel<<<1, 1024, 0, stream>>>(cnt, rowptr);
    initcur_kernel<<<(N_NODES + 255) / 256, 256, 0, stream>>>(rowptr, cursor);
    scatter_kernel<<<(N_EDGES + 255) / 256, 256, 0, stream>>>(esrc, edst, cursor, srcs, dsts);
  }
  const int* esrc_use = use_sorted ? srcs : esrc;
  const int* edst_use = use_sorted ? dsts : edst;

  embed_kernel<<<N_NODES, 128, 0, stream>>>(node_h, emb_W1, emb_b1, emb_W2, emb_b2,
                                            norm_g, norm_b, s, v);
  for (int i = 0; i < 3; ++i) {
    hipMemsetAsync(smsg, 0, (size_t)N_NODES * 176 * sizeof(float), stream);
    edge_gemm_kernel<<<N_EDGES / TE, 256, 0, stream>>>(
        s, v, coords, esrc_use, edst_use, smsg, vmsg,
        em_Wh + i * H_DIM * H_DIM, em_Wu + i * H_DIM * V_DIM,
        wsb + (size_t)i * S_DIM * WSTK, em_bs + i * S_DIM,
        em_Wg + i * S_DIM * V_DIM, em_bg + i * V_DIM,
        em_lng + i * S_DIM, em_lnb + i * S_DIM);
    node_update_kernel<<<N_NODES / 4, 256, 0, stream>>>(
        s, v, smsg, vmsg,
        nu_Wh + i * V_DIM * V_DIM, nu_Wu + i * V_DIM * V_DIM,
        nu_Ws + i * 144 * S_DIM, nu_bs + i * S_DIM,
        nu_Wg + i * S_DIM * V_DIM, nu_bg + i * V_DIM,
        nu_lng + i * S_DIM, nu_lnb + i * S_DIM,
        ln_g + i * S_DIM, ln_b + i * S_DIM);
  }
}

// Round 13
// 2524.297 us; speedup vs baseline: 2.9730x; 2.9730x over previous
//
#include <hip/hip_runtime.h>
#include <math.h>

#define N_NODES 25000
#define N_EDGES 800000
#define IN_SZ 64
#define S_DIM 128
#define V_DIM 16
#define H_DIM 17
#define GVP_EPS 1e-8f
#define LN_EPS 1e-5f
#define INV_Z 0.1f
#define TE 64    // edges per block (16 per wave for per-edge phases)
#define WSTK 160 // K padded (145 -> 160) for 5 chunks of 32

// ---- LDS layout (float offsets) ----
// ZF [64][132]: P1 scratch ve[3][20]@0..59, vh[3][20]@64..123 (f32);
//   z-stage overlays bf16 Z (k=0..159) on words 0..79; GEMM writes f32 feats
//   to words 0..127 (per-m-tile barriers make the overlay safe); P3c writes
//   the scalar message in-place over feats.
// VU [64][66]: vu@0..47, sh@48..64 (f32).
// WhL 289; WuL 272; stile/dtile int[64].
#define ZF_O 0
#define ZSTR 132
#define VU_O 8448
#define VUSTR 66
#define WHL_O 12672
#define WUL_O 12961
#define ST_O 13233
#define DT_O 13297
#define LDS_F 13361  // 53444 B -> 3 blocks/CU

typedef __attribute__((ext_vector_type(8))) short bf16x8;
typedef __attribute__((ext_vector_type(4))) float f32x4;

__device__ __forceinline__ float wave_sum(float x) {
#pragma unroll
  for (int off = 32; off; off >>= 1) x += __shfl_xor(x, off, 64);
  return x;
}

__device__ __forceinline__ float sum16(float x) {
#pragma unroll
  for (int off = 1; off < 16; off <<= 1) x += __shfl_xor(x, off, 64);
  return x;
}

__device__ __forceinline__ float silu_f(float x) { return x / (1.0f + __expf(-x)); }

__device__ __forceinline__ unsigned short bf16r(float x) {
  unsigned int u = __float_as_uint(x);
  return (unsigned short)((u + 0x7fffu + ((u >> 16) & 1u)) >> 16);
}
__device__ __forceinline__ unsigned int pk2(float a, float b) {
  return (unsigned int)bf16r(a) | ((unsigned int)bf16r(b) << 16);
}

__device__ __forceinline__ void lds_fence() {
  asm volatile("s_waitcnt lgkmcnt(0)" ::: "memory");
}

// reduce 16 partials across a 16-lane group; lane l16 gets total of index l16
__device__ __forceinline__ float reduce_scatter16(const float pu[16], int l16) {
  float r8[8];
#pragma unroll
  for (int u = 0; u < 8; ++u) {
    const float keep = (l16 & 8) ? pu[u + 8] : pu[u];
    const float send = (l16 & 8) ? pu[u] : pu[u + 8];
    r8[u] = keep + __shfl_xor(send, 8, 64);
  }
  float r4[4];
#pragma unroll
  for (int u = 0; u < 4; ++u) {
    const float keep = (l16 & 4) ? r8[u + 4] : r8[u];
    const float send = (l16 & 4) ? r8[u] : r8[u + 4];
    r4[u] = keep + __shfl_xor(send, 4, 64);
  }
  float r2[2];
#pragma unroll
  for (int u = 0; u < 2; ++u) {
    const float keep = (l16 & 2) ? r4[u + 2] : r4[u];
    const float send = (l16 & 2) ? r4[u] : r4[u + 2];
    r2[u] = keep + __shfl_xor(send, 2, 64);
  }
  const float keep = (l16 & 1) ? r2[1] : r2[0];
  const float send = (l16 & 1) ? r2[0] : r2[1];
  return keep + __shfl_xor(send, 1, 64);
}

// ---------------------------------------------------------------- embed
__global__ __launch_bounds__(128) void embed_kernel(
    const float* __restrict__ node_h,
    const float* __restrict__ W1, const float* __restrict__ b1,
    const float* __restrict__ W2, const float* __restrict__ b2,
    const float* __restrict__ g, const float* __restrict__ b,
    float* __restrict__ s, float* __restrict__ v) {
  const int n = blockIdx.x, tid = threadIdx.x;
  __shared__ float hb[IN_SZ];
  __shared__ float h1[S_DIM];
  __shared__ float red[4];
  if (tid < IN_SZ) hb[tid] = node_h[n * IN_SZ + tid];
  __syncthreads();
  float acc = b1[tid];
#pragma unroll 8
  for (int k = 0; k < IN_SZ; ++k) acc += hb[k] * W1[k * S_DIM + tid];
  float x = silu_f(acc);
  h1[tid] = x;
  __syncthreads();
  float acc2 = b2[tid];
#pragma unroll 8
  for (int k = 0; k < S_DIM; ++k) acc2 += h1[k] * W2[k * S_DIM + tid];
  float y = silu_f(acc2);
  const int wv = tid >> 6, lane = tid & 63;
  float sm = wave_sum(y);
  float sq = wave_sum(y * y);
  if (lane == 0) { red[wv] = sm; red[2 + wv] = sq; }
  __syncthreads();
  float tot = red[0] + red[1], tot2 = red[2] + red[3];
  float mu = tot * (1.0f / 128.0f);
  float var = tot2 * (1.0f / 128.0f) - mu * mu;
  float inv = rsqrtf(var + LN_EPS);
  s[n * S_DIM + tid] = (y - mu) * inv * g[tid] + b[tid];
  if (tid < 48) v[n * 48 + tid] = 0.0f;
}

// ---------------------------------------------------------------- sort infra
__global__ __launch_bounds__(256) void hist_kernel(const int* __restrict__ edst,
                                                   int* __restrict__ cnt) {
  int e = blockIdx.x * 256 + threadIdx.x;
  if (e < N_EDGES) atomicAdd(&cnt[edst[e]], 1);
}

__global__ __launch_bounds__(1024) void scan_kernel(const int* __restrict__ cnt,
                                                    int* __restrict__ rowptr) {
  __shared__ int wsum[16];
  __shared__ int carry_s;
  const int t = threadIdx.x, w = t >> 6, ln = t & 63;
  if (t == 0) carry_s = 0;
  __syncthreads();
  for (int base = 0; base < N_NODES; base += 1024) {
    const int idx = base + t;
    const int x = (idx < N_NODES) ? cnt[idx] : 0;
    int incl = x;
#pragma unroll
    for (int off = 1; off < 64; off <<= 1) {
      const int y = __shfl_up(incl, off, 64);
      if (ln >= off) incl += y;
    }
    if (ln == 63) wsum[w] = incl;
    __syncthreads();
    int woff = 0;
    for (int k = 0; k < w; ++k) woff += wsum[k];
    const int carry = carry_s;
    if (idx < N_NODES) rowptr[idx] = carry + woff + incl - x;
    __syncthreads();
    if (t == 1023) carry_s = carry + woff + incl;
    __syncthreads();
  }
  if (threadIdx.x == 0) rowptr[N_NODES] = carry_s;
}

__global__ __launch_bounds__(256) void initcur_kernel(const int* __restrict__ rowptr,
                                                      int* __restrict__ cursor) {
  int i = blockIdx.x * 256 + threadIdx.x;
  if (i < N_NODES) cursor[i] = rowptr[i];
}

__global__ __launch_bounds__(256) void scatter_kernel(const int* __restrict__ esrc,
                                                      const int* __restrict__ edst,
                                                      int* __restrict__ cursor,
                                                      int* __restrict__ srcs,
                                                      int* __restrict__ dsts) {
  int e = blockIdx.x * 256 + threadIdx.x;
  if (e < N_EDGES) {
    const int d = edst[e];
    const int p = atomicAdd(&cursor[d], 1);
    srcs[p] = esrc[e];
    dsts[p] = d;
  }
}

// ---------------------------------------------------------------- WsT prep
// bf16 transposed+padded Ws: WsT[l][n][k] = Ws[l][k][n] (k<145), else 0.
__global__ __launch_bounds__(256) void wst_prep_kernel(const float* __restrict__ Ws,
                                                       unsigned short* __restrict__ WsT) {
  const int idx = blockIdx.x * 256 + threadIdx.x;
  if (idx >= 3 * S_DIM * WSTK) return;
  const int l = idx / (S_DIM * WSTK);
  const int rr = idx - l * (S_DIM * WSTK);
  const int n = rr / WSTK, k = rr - n * WSTK;
  const float x = (k < 145) ? Ws[(size_t)l * 145 * S_DIM + (size_t)k * S_DIM + n] : 0.0f;
  WsT[idx] = bf16r(x);
}

// ---------------------------------------------------------------- edge kernel
// Column-split MFMA: wave wv owns col tiles nt = {2wv, 2wv+1}; its B-slice
// (10 KB) is preloaded into 40 VGPRs and reused for all 64 edges (4 m-tiles).
// Per m-tile: {readA -> barrier -> MFMA -> write feats} keeps the feats-over-z
// overlay race-free (rows disjoint across iterations).
__global__ __launch_bounds__(256, 3) void edge_gemm_kernel(
    const float* __restrict__ s, const float* __restrict__ v,
    const float* __restrict__ coords,
    const int* __restrict__ srcs, const int* __restrict__ dsts,
    float* __restrict__ smsg, float* __restrict__ vmsg,
    const float* __restrict__ Wh, const float* __restrict__ Wu,
    const unsigned short* __restrict__ WsT, const float* __restrict__ bs,
    const float* __restrict__ Wg, const float* __restrict__ bg,
    const float* __restrict__ lng, const float* __restrict__ lnb) {
  __shared__ float L[LDS_F];
  const int t = threadIdx.x;
  const int wv = t >> 6, ln = t & 63;
  const int g = ln >> 4, l16 = ln & 15;
  const int e0 = blockIdx.x * TE;
  const int nt0 = 2 * wv;

  // ---- B-slice preload (10 KB/wave, in flight during P1)
  bf16x8 bfr[2][5];
#pragma unroll
  for (int nn = 0; nn < 2; ++nn) {
    const unsigned short* wrow = WsT + (size_t)((nt0 + nn) * 16 + l16) * WSTK + g * 8;
#pragma unroll
    for (int kc = 0; kc < 5; ++kc)
      bfr[nn][kc] = *(const bf16x8*)(wrow + kc * 32);
  }

  int* stile = (int*)&L[ST_O];
  int* dtile = (int*)&L[DT_O];
  if (t < TE) { stile[t] = srcs[e0 + t]; dtile[t] = dsts[e0 + t]; }
  for (int k = t; k < H_DIM * H_DIM; k += 256) L[WHL_O + k] = Wh[k];
  for (int k = t; k < H_DIM * V_DIM; k += 256) L[WUL_O + k] = Wu[k];
  __syncthreads();  // barrier #1

  const int ew0 = wv * 16;
  const int lc = ln % 3, lq = ln / 3;

  // ---- P1a: gather ve (transposed [c][20]) into ZF[e][0..59]
  for (int i = 0; i < 16; ++i) {
    const int e = ew0 + i, src = stile[e];
    if (ln < 48) {
      L[ZF_O + e * ZSTR + lc * 20 + lq + 1] = v[(size_t)src * 48 + ln];
    } else if (ln < 51) {
      const int c = ln - 48;
      L[ZF_O + e * ZSTR + c * 20] = coords[src * 3 + c] - coords[dtile[e] * 3 + c];
    }
  }
  lds_fence();

  // ---- P1b: vh (into ZF[e][64..123])
  {
    float wh[H_DIM];
    if (ln < 51) {
#pragma unroll
      for (int vv = 0; vv < H_DIM; ++vv) wh[vv] = L[WHL_O + vv * H_DIM + lq];
    }
    for (int i = 0; i < 16; ++i) {
      const int e = ew0 + i;
      if (ln < 51) {
        const int b = ZF_O + e * ZSTR + lc * 20;
        const float4 v0 = *(const float4*)&L[b + 0];
        const float4 v1 = *(const float4*)&L[b + 4];
        const float4 v2 = *(const float4*)&L[b + 8];
        const float4 v3 = *(const float4*)&L[b + 12];
        const float vl = L[b + 16];
        float a = wh[0] * v0.x + wh[1] * v0.y + wh[2] * v0.z + wh[3] * v0.w
                + wh[4] * v1.x + wh[5] * v1.y + wh[6] * v1.z + wh[7] * v1.w
                + wh[8] * v2.x + wh[9] * v2.y + wh[10] * v2.z + wh[11] * v2.w
                + wh[12] * v3.x + wh[13] * v3.y + wh[14] * v3.z + wh[15] * v3.w
                + wh[16] * vl;
        L[ZF_O + e * ZSTR + 64 + lc * 20 + lq] = a;
      }
    }
  }
  lds_fence();

  // ---- P1c: sh -> VU[e][48..64]
  for (int i = 0; i < 16; ++i) {
    const int e = ew0 + i;
    if (ln < H_DIM) {
      const float x0 = L[ZF_O + e * ZSTR + 64 + 0 + ln];
      const float x1 = L[ZF_O + e * ZSTR + 64 + 20 + ln];
      const float x2 = L[ZF_O + e * ZSTR + 64 + 40 + ln];
      L[VU_O + e * VUSTR + 48 + ln] = sqrtf(x0 * x0 + x1 * x1 + x2 * x2 + GVP_EPS);
    }
  }
  // ---- P1d: vu -> VU[e][u*3+c]
  {
    float wu[H_DIM];
    if (ln < 48) {
#pragma unroll
      for (int h = 0; h < H_DIM; ++h) wu[h] = L[WUL_O + h * V_DIM + lq];
    }
    for (int i = 0; i < 16; ++i) {
      const int e = ew0 + i;
      if (ln < 48) {
        const int b = ZF_O + e * ZSTR + 64 + lc * 20;
        const float4 v0 = *(const float4*)&L[b + 0];
        const float4 v1 = *(const float4*)&L[b + 4];
        const float4 v2 = *(const float4*)&L[b + 8];
        const float4 v3 = *(const float4*)&L[b + 12];
        const float vl = L[b + 16];
        float a = wu[0] * v0.x + wu[1] * v0.y + wu[2] * v0.z + wu[3] * v0.w
                + wu[4] * v1.x + wu[5] * v1.y + wu[6] * v1.z + wu[7] * v1.w
                + wu[8] * v2.x + wu[9] * v2.y + wu[10] * v2.z + wu[11] * v2.w
                + wu[12] * v3.x + wu[13] * v3.y + wu[14] * v3.z + wu[15] * v3.w
                + wu[16] * vl;
        L[VU_O + e * VUSTR + lq * 3 + lc] = a;
      }
    }
  }
  lds_fence();

  // ---- Z stage: bf16 Z row (k 0..127 = s cols, 128..144 = sh, rest 0) into
  //      words 0..79 of own ZF row (ve/vh dead).  4 lanes/edge.
  {
    const int le = ln >> 2, q = ln & 3;
    const int e = ew0 + le;
    char* zb = (char*)&L[ZF_O + e * ZSTR];
    if (q < 3) {
      const float* sp = &s[(size_t)stile[e] * S_DIM + q * 40];
#pragma unroll
      for (int c = 0; c < 5; ++c) {
        const float4 x0 = *(const float4*)(sp + c * 8);
        const float4 x1 = *(const float4*)(sp + c * 8 + 4);
        uint4 w;
        w.x = pk2(x0.x, x0.y); w.y = pk2(x0.z, x0.w);
        w.z = pk2(x1.x, x1.y); w.w = pk2(x1.z, x1.w);
        *(uint4*)(zb + (q * 40 + c * 8) * 2) = w;
      }
    } else {
      const float* sp = &s[(size_t)stile[e] * S_DIM + 120];
      const float4 x0 = *(const float4*)(sp);
      const float4 x1 = *(const float4*)(sp + 4);
      uint4 w;
      w.x = pk2(x0.x, x0.y); w.y = pk2(x0.z, x0.w);
      w.z = pk2(x1.x, x1.y); w.w = pk2(x1.z, x1.w);
      *(uint4*)(zb + 240) = w;  // k=120..127
      float shv[17];
#pragma unroll
      for (int i2 = 0; i2 < 17; ++i2) shv[i2] = L[VU_O + e * VUSTR + 48 + i2];
      uint4 w1, w2, w3, w4;
      w1.x = pk2(shv[0], shv[1]);  w1.y = pk2(shv[2], shv[3]);
      w1.z = pk2(shv[4], shv[5]);  w1.w = pk2(shv[6], shv[7]);
      w2.x = pk2(shv[8], shv[9]);  w2.y = pk2(shv[10], shv[11]);
      w2.z = pk2(shv[12], shv[13]); w2.w = pk2(shv[14], shv[15]);
      w3.x = pk2(shv[16], 0.0f); w3.y = 0u; w3.z = 0u; w3.w = 0u;
      w4.x = 0u; w4.y = 0u; w4.z = 0u; w4.w = 0u;
      *(uint4*)(zb + 256) = w1;  // k=128..135
      *(uint4*)(zb + 272) = w2;  // k=136..143
      *(uint4*)(zb + 288) = w3;  // k=144..151
      *(uint4*)(zb + 304) = w4;  // k=152..159
    }
  }
  lds_fence();
  __syncthreads();  // barrier #2: all Z rows ready

  // ---- P2: MFMA, per-m-tile pipeline (barriers #3..#6)
  for (int mt = 0; mt < 4; ++mt) {
    bf16x8 afr[5];
    const char* arow = (const char*)&L[ZF_O + (mt * 16 + l16) * ZSTR] + g * 16;
#pragma unroll
    for (int kc = 0; kc < 5; ++kc)
      afr[kc] = *(const bf16x8*)(arow + kc * 64);
    lds_fence();      // A-frags in regs
    __syncthreads();  // all waves done reading this m-tile's rows
#pragma unroll
    for (int nn = 0; nn < 2; ++nn) {
      const float bsv = bs[(nt0 + nn) * 16 + l16];
      f32x4 fa = {bsv, bsv, bsv, bsv};
#pragma unroll
      for (int kc = 0; kc < 5; ++kc)
        fa = __builtin_amdgcn_mfma_f32_16x16x32_bf16(afr[kc], bfr[nn][kc], fa, 0, 0, 0);
      // silu + write feats: row = mt*16 + g*4 + r, col = (nt0+nn)*16 + l16
#pragma unroll
      for (int r = 0; r < 4; ++r)
        L[ZF_O + (mt * 16 + g * 4 + r) * ZSTR + (nt0 + nn) * 16 + l16] = silu_f(fa[r]);
    }
  }
  lds_fence();
  __syncthreads();  // barrier #7: full feats rows ready

  // ---- per-edge phases (wave-local, edges ew0..ew0+15)
  // lane tile: group g owns edges ew0+g*4..+3; cols {l16*4..+3, 64+l16*4..+3}
  float f[4][8];
#pragma unroll
  for (int i = 0; i < 4; ++i) {
    const int e = ew0 + g * 4 + i;
    const float4 a = *(const float4*)&L[ZF_O + e * ZSTR + l16 * 4];
    const float4 b = *(const float4*)&L[ZF_O + e * ZSTR + 64 + l16 * 4];
    f[i][0] = a.x; f[i][1] = a.y; f[i][2] = a.z; f[i][3] = a.w;
    f[i][4] = b.x; f[i][5] = b.y; f[i][6] = b.z; f[i][7] = b.w;
  }
  lds_fence();

  // ---- P3a: gate (Wg from global, L1-resident)
  const float bgv = bg[l16];
  float gate_i[4];
#pragma unroll
  for (int pr = 0; pr < 2; ++pr) {
    float puA[16], puB[16];
    const int pA = pr * 2, pB = pr * 2 + 1;
#pragma unroll
    for (int u = 0; u < 16; ++u) { puA[u] = 0.0f; puB[u] = 0.0f; }
#pragma unroll
    for (int j = 0; j < 8; ++j) {
      const int fc = (j < 4) ? (l16 * 4 + j) : (64 + l16 * 4 + (j - 4));
      const float4 w0 = *(const float4*)&Wg[fc * V_DIM + 0];
      const float4 w1 = *(const float4*)&Wg[fc * V_DIM + 4];
      const float4 w2 = *(const float4*)&Wg[fc * V_DIM + 8];
      const float4 w3 = *(const float4*)&Wg[fc * V_DIM + 12];
      const float fA = f[pA][j], fB = f[pB][j];
      puA[0] += fA * w0.x; puA[1] += fA * w0.y; puA[2] += fA * w0.z; puA[3] += fA * w0.w;
      puA[4] += fA * w1.x; puA[5] += fA * w1.y; puA[6] += fA * w1.z; puA[7] += fA * w1.w;
      puA[8] += fA * w2.x; puA[9] += fA * w2.y; puA[10] += fA * w2.z; puA[11] += fA * w2.w;
      puA[12] += fA * w3.x; puA[13] += fA * w3.y; puA[14] += fA * w3.z; puA[15] += fA * w3.w;
      puB[0] += fB * w0.x; puB[1] += fB * w0.y; puB[2] += fB * w0.z; puB[3] += fB * w0.w;
      puB[4] += fB * w1.x; puB[5] += fB * w1.y; puB[6] += fB * w1.z; puB[7] += fB * w1.w;
      puB[8] += fB * w2.x; puB[9] += fB * w2.y; puB[10] += fB * w2.z; puB[11] += fB * w2.w;
      puB[12] += fB * w3.x; puB[13] += fB * w3.y; puB[14] += fB * w3.z; puB[15] += fB * w3.w;
    }
    gate_i[pA] = silu_f(reduce_scatter16(puA, l16) + bgv);
    gate_i[pB] = silu_f(reduce_scatter16(puB, l16) + bgv);
  }

  // ---- P3b: vm in-place in VU (channel u = l16)
#pragma unroll
  for (int i = 0; i < 4; ++i) {
    const int e = ew0 + g * 4 + i;
    const int b = VU_O + e * VUSTR + l16 * 3;
    const float gt = gate_i[i];
    const float vm0 = L[b + 0] * gt;
    const float vm1 = L[b + 1] * gt;
    const float vm2 = L[b + 2] * gt;
    float ss = sum16(vm0 * vm0 + vm1 * vm1 + vm2 * vm2);
    const float sc = INV_Z * rsqrtf(ss * (1.0f / 16.0f) + GVP_EPS);
    L[b + 0] = vm0 * sc;
    L[b + 1] = vm1 * sc;
    L[b + 2] = vm2 * sc;
  }

  // ---- P3c: scalar message in-place over feats (wave-owned rows)
  {
    const float4 lgA = *(const float4*)&lng[l16 * 4];
    const float4 lgB = *(const float4*)&lng[64 + l16 * 4];
    const float4 lbA = *(const float4*)&lnb[l16 * 4];
    const float4 lbB = *(const float4*)&lnb[64 + l16 * 4];
#pragma unroll
    for (int i = 0; i < 4; ++i) {
      float s1 = 0.0f, s2 = 0.0f;
#pragma unroll
      for (int j = 0; j < 8; ++j) { s1 += f[i][j]; s2 += f[i][j] * f[i][j]; }
      s1 = sum16(s1); s2 = sum16(s2);
      const float mu = s1 * (1.0f / 128.0f);
      const float var = s2 * (1.0f / 128.0f) - mu * mu;
      const float inv = rsqrtf(var + LN_EPS);
      const int e = ew0 + g * 4 + i;
      float4 o0, o1;
      o0.x = ((f[i][0] - mu) * inv * lgA.x + lbA.x) * INV_Z;
      o0.y = ((f[i][1] - mu) * inv * lgA.y + lbA.y) * INV_Z;
      o0.z = ((f[i][2] - mu) * inv * lgA.z + lbA.z) * INV_Z;
      o0.w = ((f[i][3] - mu) * inv * lgA.w + lbA.w) * INV_Z;
      o1.x = ((f[i][4] - mu) * inv * lgB.x + lbB.x) * INV_Z;
      o1.y = ((f[i][5] - mu) * inv * lgB.y + lbB.y) * INV_Z;
      o1.z = ((f[i][6] - mu) * inv * lgB.z + lbB.z) * INV_Z;
      o1.w = ((f[i][7] - mu) * inv * lgB.w + lbB.w) * INV_Z;
      *(float4*)&L[ZF_O + e * ZSTR + l16 * 4] = o0;
      *(float4*)&L[ZF_O + e * ZSTR + 64 + l16 * 4] = o1;
    }
  }
  lds_fence();

  // ---- P4: per-wave run aggregation over 16 edges
  int r = 0;
  while (r < 16) {
    const int d = dtile[ew0 + r];
    int rend = r + 1;
    while (rend < 16 && dtile[ew0 + rend] == d) ++rend;
    float a0 = 0.0f, a1 = 0.0f, a2 = 0.0f;
    for (int i = r; i < rend; ++i) {
      a0 += L[ZF_O + (ew0 + i) * ZSTR + ln];
      a1 += L[ZF_O + (ew0 + i) * ZSTR + 64 + ln];
      if (ln < 48) a2 += L[VU_O + (ew0 + i) * VUSTR + ln];
    }
    atomicAdd(&smsg[(size_t)d * S_DIM + ln], a0);
    atomicAdd(&smsg[(size_t)d * S_DIM + 64 + ln], a1);
    if (ln < 48) atomicAdd(&vmsg[(size_t)d * 48 + ln], a2);
    r = rend;
  }
}

// ---------------------------------------------------------------- node update
__global__ __launch_bounds__(256) void node_update_kernel(
    float* __restrict__ s, float* __restrict__ v,
    const float* __restrict__ smsg, const float* __restrict__ vmsg,
    const float* __restrict__ Wh, const float* __restrict__ Wu,
    const float* __restrict__ Ws, const float* __restrict__ bs,
    const float* __restrict__ Wg, const float* __restrict__ bg,
    const float* __restrict__ lng, const float* __restrict__ lnb,
    const float* __restrict__ og, const float* __restrict__ ob) {
  const int wv = threadIdx.x >> 6, lane = threadIdx.x & 63;
  const int n = blockIdx.x * 4 + wv;

  __shared__ float z[4][146];
  __shared__ float vel[4][48];
  __shared__ float vhl[4][48];
  __shared__ float fe[4][128];
  __shared__ float ga[4][16];

  float s0 = s[n * S_DIM + lane] + smsg[n * S_DIM + lane];
  float s1 = s[n * S_DIM + 64 + lane] + smsg[n * S_DIM + 64 + lane];
  float sm_ = wave_sum(s0 + s1), sq_ = wave_sum(s0 * s0 + s1 * s1);
  float mu = sm_ * (1.0f / 128.0f), var = sq_ * (1.0f / 128.0f) - mu * mu;
  float inv = rsqrtf(var + LN_EPS);
  float sa0 = (s0 - mu) * inv * og[lane] + ob[lane];
  float sa1 = (s1 - mu) * inv * og[64 + lane] + ob[64 + lane];
  z[wv][lane] = sa0; z[wv][64 + lane] = sa1;
  float vvr = 0.0f;
  if (lane < 48) vvr = v[n * 48 + lane] + vmsg[n * 48 + lane];
  float n2 = wave_sum(vvr * vvr);
  float rms = sqrtf(n2 * (1.0f / 16.0f) + GVP_EPS);
  float vln = vvr / rms;
  if (lane < 48) vel[wv][lane] = vln;
  __syncthreads();

  if (lane < 48) {
    int h = lane / 3, c = lane - 3 * h;
    float a = 0.0f;
#pragma unroll
    for (int vv = 0; vv < V_DIM; ++vv) a += vel[wv][vv * 3 + c] * Wh[vv * V_DIM + h];
    vhl[wv][lane] = a;
  }
  __syncthreads();

  if (lane < V_DIM) {
    float a = vhl[wv][lane * 3], b_ = vhl[wv][lane * 3 + 1], c_ = vhl[wv][lane * 3 + 2];
    z[wv][128 + lane] = sqrtf(a * a + b_ * b_ + c_ * c_ + GVP_EPS);
  }
  float vur = 0.0f;
  if (lane < 48) {
    int u = lane / 3, c = lane - 3 * u;
#pragma unroll
    for (int h = 0; h < V_DIM; ++h) vur += vhl[wv][h * 3 + c] * Wu[h * V_DIM + u];
  }
  __syncthreads();

  float f0 = bs[lane], f1 = bs[64 + lane];
#pragma unroll 4
  for (int k = 0; k < 144; ++k) {
    float zz = z[wv][k];
    f0 += zz * Ws[k * S_DIM + lane];
    f1 += zz * Ws[k * S_DIM + 64 + lane];
  }
  f0 = silu_f(f0); f1 = silu_f(f1);
  fe[wv][lane] = f0; fe[wv][64 + lane] = f1;
  __syncthreads();

  {
    int u = lane >> 2, q = lane & 3;
    float p = 0.0f;
#pragma unroll 8
    for (int k = q * 32; k < q * 32 + 32; ++k) p += fe[wv][k] * Wg[k * V_DIM + u];
    p += __shfl_xor(p, 1, 64);
    p += __shfl_xor(p, 2, 64);
    if (q == 0) ga[wv][u] = silu_f(p + bg[u]);
  }
  float sm2 = wave_sum(f0 + f1), sq2 = wave_sum(f0 * f0 + f1 * f1);
  float mu2 = sm2 * (1.0f / 128.0f), var2 = sq2 * (1.0f / 128.0f) - mu2 * mu2;
  float inv2 = rsqrtf(var2 + LN_EPS);
  float t0 = sa0 + (f0 - mu2) * inv2 * lng[lane] + lnb[lane];
  float t1 = sa1 + (f1 - mu2) * inv2 * lng[64 + lane] + lnb[64 + lane];
  float sm3 = wave_sum(t0 + t1), sq3 = wave_sum(t0 * t0 + t1 * t1);
  float mu3 = sm3 * (1.0f / 128.0f), var3 = sq3 * (1.0f / 128.0f) - mu3 * mu3;
  float inv3 = rsqrtf(var3 + LN_EPS);
  s[n * S_DIM + lane] = (t0 - mu3) * inv3 * og[lane] + ob[lane];
  s[n * S_DIM + 64 + lane] = (t1 - mu3) * inv3 * og[64 + lane] + ob[64 + lane];
  __syncthreads();

  float vo = 0.0f;
  if (lane < 48) { int u = lane / 3; vo = vur * ga[wv][u]; }
  float n22 = wave_sum(vo * vo);
  float rms2 = sqrtf(n22 * (1.0f / 16.0f) + GVP_EPS);
  float vr = vo / rms2;
  float v2 = (lane < 48) ? (vln + vr) : 0.0f;
  float n23 = wave_sum(v2 * v2);
  float rms3 = sqrtf(n23 * (1.0f / 16.0f) + GVP_EPS);
  if (lane < 48) v[n * 48 + lane] = v2 / rms3;
}

// ---------------------------------------------------------------- launch
extern "C" void kernel_launch(void* const* d_in, const int* in_sizes, int n_in,
                              void* d_out, int out_size, void* d_ws, size_t ws_size,
                              hipStream_t stream) {
  const float* node_h = (const float*)d_in[0];
  const float* coords = (const float*)d_in[1];
  const int* esrc = (const int*)d_in[2];
  const int* edst = (const int*)d_in[3];
  const float* emb_W1 = (const float*)d_in[4];
  const float* emb_b1 = (const float*)d_in[5];
  const float* emb_W2 = (const float*)d_in[6];
  const float* emb_b2 = (const float*)d_in[7];
  const float* norm_g = (const float*)d_in[8];
  const float* norm_b = (const float*)d_in[9];
  const float* em_Wh = (const float*)d_in[10];
  const float* em_Wu = (const float*)d_in[11];
  const float* em_Ws = (const float*)d_in[12];
  const float* em_bs = (const float*)d_in[13];
  const float* em_Wg = (const float*)d_in[14];
  const float* em_bg = (const float*)d_in[15];
  const float* em_lng = (const float*)d_in[16];
  const float* em_lnb = (const float*)d_in[17];
  const float* nu_Wh = (const float*)d_in[18];
  const float* nu_Wu = (const float*)d_in[19];
  const float* nu_Ws = (const float*)d_in[20];
  const float* nu_bs = (const float*)d_in[21];
  const float* nu_Wg = (const float*)d_in[22];
  const float* nu_bg = (const float*)d_in[23];
  const float* nu_lng = (const float*)d_in[24];
  const float* nu_lnb = (const float*)d_in[25];
  const float* ln_g = (const float*)d_in[26];
  const float* ln_b = (const float*)d_in[27];

  float* s = (float*)d_out;                      // [N,128] output 0
  float* v = s + (size_t)N_NODES * S_DIM;        // [N,16,3] output 1

  float* smsg = (float*)d_ws;                    // [N,128]
  float* vmsg = smsg + (size_t)N_NODES * S_DIM;  // [N,48]
  unsigned short* wsb = (unsigned short*)(vmsg + (size_t)N_NODES * 48);  // [3][128][160] bf16
  int* rowptr = (int*)(wsb + (size_t)3 * S_DIM * WSTK);  // [N+1] (+pad)
  int* srcs = rowptr + N_NODES + 8;              // [E]
  int* dsts = srcs + N_EDGES;                    // [E]
  int* cnt = (int*)smsg;                         // alias (setup phase only)
  int* cursor = cnt + N_NODES;                   // alias (setup phase only)

  const size_t need_sorted =
      (size_t)N_NODES * 176 * sizeof(float) +
      (size_t)3 * S_DIM * WSTK * sizeof(unsigned short) +
      (size_t)(N_NODES + 1 + 8) * sizeof(int) +
      (size_t)2 * N_EDGES * sizeof(int);
  // ws_size is fixed across calls -> branch is deterministic (graph-safe).
  const bool use_sorted = ws_size >= need_sorted;

  // WsT bf16 prep (both paths use it)
  wst_prep_kernel<<<(3 * S_DIM * WSTK + 255) / 256, 256, 0, stream>>>(em_Ws, wsb);

  if (use_sorted) {
    hipMemsetAsync(cnt, 0, N_NODES * sizeof(int), stream);
    hist_kernel<<<(N_EDGES + 255) / 256, 256, 0, stream>>>(edst, cnt);
    scan_kernel<<<1, 1024, 0, stream>>>(cnt, rowptr);
    initcur_kernel<<<(N_NODES + 255) / 256, 256, 0, stream>>>(rowptr, cursor);
    scatter_kernel<<<(N_EDGES + 255) / 256, 256, 0, stream>>>(esrc, edst, cursor, srcs, dsts);
  }
  const int* esrc_use = use_sorted ? srcs : esrc;
  const int* edst_use = use_sorted ? dsts : edst;

  embed_kernel<<<N_NODES, 128, 0, stream>>>(node_h, emb_W1, emb_b1, emb_W2, emb_b2,
                                            norm_g, norm_b, s, v);
  for (int i = 0; i < 3; ++i) {
    hipMemsetAsync(smsg, 0, (size_t)N_NODES * 176 * sizeof(float), stream);
    edge_gemm_kernel<<<N_EDGES / TE, 256, 0, stream>>>(
        s, v, coords, esrc_use, edst_use, smsg, vmsg,
        em_Wh + i * H_DIM * H_DIM, em_Wu + i * H_DIM * V_DIM,
        wsb + (size_t)i * S_DIM * WSTK, em_bs + i * S_DIM,
        em_Wg + i * S_DIM * V_DIM, em_bg + i * V_DIM,
        em_lng + i * S_DIM, em_lnb + i * S_DIM);
    node_update_kernel<<<N_NODES / 4, 256, 0, stream>>>(
        s, v, smsg, vmsg,
        nu_Wh + i * V_DIM * V_DIM, nu_Wu + i * V_DIM * V_DIM,
        nu_Ws + i * 144 * S_DIM, nu_bs + i * S_DIM,
        nu_Wg + i * S_DIM * V_DIM, nu_bg + i * V_DIM,
        nu_lng + i * S_DIM, nu_lnb + i * S_DIM,
        ln_g + i * S_DIM, ln_b + i * S_DIM);
  }
}